// Round 3
// baseline (473.063 us; speedup 1.0000x reference)
//
#include <hip/hip_runtime.h>
#include <stdint.h>

#define TS 2048
#define CD 128
#define NB 8
#define NROWS (NB*TS)          // 16384
#define RPB 8                  // rows per block in projection kernels
#define SCALE 0.08838834764831845f  // 1/sqrt(128)

// ---- Kernel 1: Q = E@Wq^T, K = E@Wk^T (fp32), 8 rows per block ----
__global__ __launch_bounds__(128) void proj_qk(
    const float* __restrict__ E, const float* __restrict__ Wq,
    const float* __restrict__ Wk, float* __restrict__ Q, float* __restrict__ K)
{
    const int r0 = blockIdx.x * RPB, t = threadIdx.x;
    __shared__ float e[RPB][CD];
    {   // stage 8 E rows = 1024 floats (256 float4, 2 per thread)
        const float4* src = (const float4*)(E + (size_t)r0*CD);
        float4* dst = (float4*)&e[0][0];
        dst[t] = src[t];
        dst[t + 128] = src[t + 128];
    }
    __syncthreads();
    const float* wq = Wq + (size_t)t*CD;
    const float* wk = Wk + (size_t)t*CD;
    float aq[RPB], ak[RPB];
    #pragma unroll
    for (int i = 0; i < RPB; i++) { aq[i] = 0.f; ak[i] = 0.f; }
    #pragma unroll
    for (int c = 0; c < CD; c += 4) {
        float4 a = *(const float4*)(wq + c);
        float4 b = *(const float4*)(wk + c);
        #pragma unroll
        for (int i = 0; i < RPB; i++) {
            float e0 = e[i][c+0], e1 = e[i][c+1], e2 = e[i][c+2], e3 = e[i][c+3];
            aq[i] += a.x*e0 + a.y*e1 + a.z*e2 + a.w*e3;
            ak[i] += b.x*e0 + b.y*e1 + b.z*e2 + b.w*e3;
        }
    }
    #pragma unroll
    for (int i = 0; i < RPB; i++) {
        Q[(size_t)(r0+i)*CD + t] = aq[i];
        K[(size_t)(r0+i)*CD + t] = ak[i];
    }
}

// ---- Kernel 2: scores = Q@K^T (unscaled), running top-3/row, 3-term softmax ----
#define TQ 32
#define TJ 128
#define CCK 64

__global__ __launch_bounds__(256) void scores_top3(
    const float* __restrict__ Q, const float* __restrict__ K, float* __restrict__ TOP)
{
    const int b  = blockIdx.x;           // 512 blocks = 8 n * 64 q-tiles
    const int n  = b >> 6;
    const int q0 = (b & 63) * TQ;
    const float* Qb = Q + ((size_t)n*TS + q0) * CD;
    const float* Kb = K + (size_t)n*TS*CD;
    const int tid = threadIdx.x;
    const int tj = tid & 31, tq = tid >> 5;   // tq in [0,8)

    __shared__ float sQ[TQ][CD];          // 16 KB
    __shared__ float sKt[CCK][TJ + 1];    // 64x129 fp32 = 33 KB (c-major)

    {   // stage Q tile (32x128 contiguous floats)
        const float4* src = (const float4*)Qb;
        float4* dst = (float4*)&sQ[0][0];
        #pragma unroll
        for (int i = 0; i < 4; i++) dst[tid + 256*i] = src[tid + 256*i];
    }

    float v0 = -3e38f, v1 = -3e38f, v2 = -3e38f;   // running top-3 (row = tid, tid<32)
    int   i0 = 0, i1 = 0, i2 = 0;

    for (int j0 = 0; j0 < TS; j0 += TJ) {
        float acc[4][4];
        #pragma unroll
        for (int i = 0; i < 4; i++)
            #pragma unroll
            for (int u = 0; u < 4; u++) acc[i][u] = 0.f;

        for (int cc = 0; cc < CD; cc += CCK) {
            __syncthreads();   // protect sKt/sbuf from previous phase
            #pragma unroll
            for (int i = 0; i < 8; i++) {      // stage K chunk, transposed
                int x = tid + 256*i;           // 0..2047
                int j = x >> 4, c4 = (x & 15) * 4;
                float4 v = *(const float4*)(Kb + (size_t)(j0 + j)*CD + cc + c4);
                sKt[c4+0][j] = v.x; sKt[c4+1][j] = v.y;
                sKt[c4+2][j] = v.z; sKt[c4+3][j] = v.w;
            }
            __syncthreads();
            for (int c4 = 0; c4 < CCK; c4 += 4) {
                float4 qv[4];
                #pragma unroll
                for (int i = 0; i < 4; i++)
                    qv[i] = *(const float4*)&sQ[tq*4+i][cc + c4];
                #pragma unroll
                for (int d = 0; d < 4; d++) {
                    float kv0 = sKt[c4+d][tj];
                    float kv1 = sKt[c4+d][tj+32];
                    float kv2 = sKt[c4+d][tj+64];
                    float kv3 = sKt[c4+d][tj+96];
                    #pragma unroll
                    for (int i = 0; i < 4; i++) {
                        float q = (d==0)?qv[i].x:(d==1)?qv[i].y:(d==2)?qv[i].z:qv[i].w;
                        acc[i][0] += q*kv0; acc[i][1] += q*kv1;
                        acc[i][2] += q*kv2; acc[i][3] += q*kv3;
                    }
                }
            }
        }
        // dump 32x128 score tile into LDS (reuse sKt storage, stride 129)
        __syncthreads();
        float* sbuf = &sKt[0][0];
        #pragma unroll
        for (int i = 0; i < 4; i++)
            #pragma unroll
            for (int u = 0; u < 4; u++)
                sbuf[(size_t)(tq*4+i)*(TJ+1) + tj + 32*u] = acc[i][u];
        __syncthreads();
        if (tid < TQ) {   // thread tid owns q-row tid: merge 128 candidates
            const float* row = sbuf + (size_t)tid*(TJ+1);
            for (int j2 = 0; j2 < TJ; j2++) {
                float v = row[j2];
                if (v > v2) {
                    int jg = j0 + j2;
                    if (v > v0)      { v2=v1;i2=i1; v1=v0;i1=i0; v0=v;i0=jg; }
                    else if (v > v1) { v2=v1;i2=i1; v1=v; i1=jg; }
                    else             { v2=v;  i2=jg; }
                }
            }
        }
    }
    if (tid < TQ) {       // 3-term softmax of scaled scores
        const int row = n*TS + q0 + tid;
        float e1 = __expf((v1 - v0)*SCALE);
        float e2 = __expf((v2 - v0)*SCALE);
        float rz = 1.0f / (1.0f + e1 + e2);
        float* dst = TOP + (size_t)row*8;
        dst[0] = rz; dst[1] = e1*rz; dst[2] = e2*rz;
        int* di = (int*)dst;
        di[4] = i0; di[5] = i1; di[6] = i2;
    }
}

// ---- Kernel 3: materialize dense fp32 attention (zeros + 3 probs per row) ----
__global__ __launch_bounds__(256) void attn_write(
    const float* __restrict__ TOP, float* __restrict__ A)
{
    const int r = blockIdx.x, t = threadIdx.x;
    const float* s = TOP + (size_t)r*8;        // uniform -> scalar loads
    const int* si = (const int*)s;
    float p0 = s[0], p1 = s[1], p2 = s[2];
    int i0 = si[4], i1 = si[5], i2 = si[6];
    const int col0 = t*8;
    float vals[8];
    #pragma unroll
    for (int u = 0; u < 8; u++) {
        int col = col0 + u;
        float v = 0.f;
        if (col == i0) v = p0;
        if (col == i1) v = p1;
        if (col == i2) v = p2;
        vals[u] = v;
    }
    float4* dst = (float4*)(A + (size_t)r*TS + col0);
    dst[0] = make_float4(vals[0], vals[1], vals[2], vals[3]);
    dst[1] = make_float4(vals[4], vals[5], vals[6], vals[7]);
}

// ---- Kernel 4: out = (sum_k p_k * E[i_k]) @ Wo^T + bo, 8 rows per block ----
__global__ __launch_bounds__(128) void out_proj(
    const float* __restrict__ E, const float* __restrict__ Wo,
    const float* __restrict__ bo, const float* __restrict__ TOP,
    float* __restrict__ OUT)
{
    const int r0 = blockIdx.x * RPB, t = threadIdx.x;
    const int n = r0 >> 11;    // all 8 rows share n (T divisible by RPB)
    __shared__ float o[RPB][CD];
    #pragma unroll
    for (int i = 0; i < RPB; i++) {
        const float* s = TOP + (size_t)(r0+i)*8;
        const int* si = (const int*)s;
        const float* e0 = E + ((size_t)n*TS + si[4])*CD;
        const float* e1 = E + ((size_t)n*TS + si[5])*CD;
        const float* e2 = E + ((size_t)n*TS + si[6])*CD;
        o[i][t] = s[0]*e0[t] + s[1]*e1[t] + s[2]*e2[t];
    }
    __syncthreads();
    const float* wr = Wo + (size_t)t*CD;
    float acc[RPB];
    float bias = bo[t];
    #pragma unroll
    for (int i = 0; i < RPB; i++) acc[i] = bias;
    #pragma unroll
    for (int c = 0; c < CD; c += 4) {
        float4 a = *(const float4*)(wr + c);
        #pragma unroll
        for (int i = 0; i < RPB; i++)
            acc[i] += a.x*o[i][c+0] + a.y*o[i][c+1] + a.z*o[i][c+2] + a.w*o[i][c+3];
    }
    #pragma unroll
    for (int i = 0; i < RPB; i++)
        OUT[(size_t)(r0+i)*CD + t] = acc[i];
}

extern "C" void kernel_launch(void* const* d_in, const int* in_sizes, int n_in,
                              void* d_out, int out_size, void* d_ws, size_t ws_size,
                              hipStream_t stream)
{
    const float* E  = (const float*)d_in[0];
    // d_in[1] = ac, unused by the forward pass
    const float* Wq = (const float*)d_in[2];
    const float* Wk = (const float*)d_in[3];
    const float* Wo = (const float*)d_in[4];
    const float* bo = (const float*)d_in[5];

    float* Q   = (float*)d_ws;                       // 16384x128 fp32 (8 MB)
    float* K   = Q + (size_t)NROWS*CD;               // 8 MB
    float* TOP = K + (size_t)NROWS*CD;               // 16384x8 fp32 (512 KB)

    float* OUT = (float*)d_out;                      // [N,T,C] fp32
    float* A   = OUT + (size_t)NROWS*CD;             // [N,1,T,T] fp32

    proj_qk    <<<NROWS/RPB, 128, 0, stream>>>(E, Wq, Wk, Q, K);
    scores_top3<<<512,       256, 0, stream>>>(Q, K, TOP);
    attn_write <<<NROWS,     256, 0, stream>>>(TOP, A);
    out_proj   <<<NROWS/RPB, 128, 0, stream>>>(E, Wo, bo, TOP, OUT);
}

// Round 4
// 426.749 us; speedup vs baseline: 1.1085x; 1.1085x over previous
//
#include <hip/hip_runtime.h>
#include <stdint.h>

#define TS 2048
#define CD 128
#define NB 8
#define NROWS (NB*TS)          // 16384
#define RPB 8                  // rows per block in projection kernels
#define SCALE 0.08838834764831845f  // 1/sqrt(128)

// ---- Kernel 1: Q = E@Wq^T, K = E@Wk^T (fp32), 8 rows per block ----
__global__ __launch_bounds__(128) void proj_qk(
    const float* __restrict__ E, const float* __restrict__ Wq,
    const float* __restrict__ Wk, float* __restrict__ Q, float* __restrict__ K)
{
    const int r0 = blockIdx.x * RPB, t = threadIdx.x;
    __shared__ float e[RPB][CD];
    {   // stage 8 E rows = 1024 floats (256 float4, 2 per thread)
        const float4* src = (const float4*)(E + (size_t)r0*CD);
        float4* dst = (float4*)&e[0][0];
        dst[t] = src[t];
        dst[t + 128] = src[t + 128];
    }
    __syncthreads();
    const float* wq = Wq + (size_t)t*CD;
    const float* wk = Wk + (size_t)t*CD;
    float aq[RPB], ak[RPB];
    #pragma unroll
    for (int i = 0; i < RPB; i++) { aq[i] = 0.f; ak[i] = 0.f; }
    #pragma unroll
    for (int c = 0; c < CD; c += 4) {
        float4 a = *(const float4*)(wq + c);
        float4 b = *(const float4*)(wk + c);
        #pragma unroll
        for (int i = 0; i < RPB; i++) {
            float e0 = e[i][c+0], e1 = e[i][c+1], e2 = e[i][c+2], e3 = e[i][c+3];
            aq[i] += a.x*e0 + a.y*e1 + a.z*e2 + a.w*e3;
            ak[i] += b.x*e0 + b.y*e1 + b.z*e2 + b.w*e3;
        }
    }
    #pragma unroll
    for (int i = 0; i < RPB; i++) {
        Q[(size_t)(r0+i)*CD + t] = aq[i];
        K[(size_t)(r0+i)*CD + t] = ak[i];
    }
}

// ---- Kernel 2: scores = Q@K^T, per-thread register top-3, one final merge ----
#define TQ 32
#define TJ 128
#define CCK 64
#define SKS 68                 // sK row stride in floats (64 + 4, 16B aligned)
#define MRS 193                // merge row stride in floats (32*6 + 1)

__global__ __launch_bounds__(256, 2) void scores_top3(
    const float* __restrict__ Q, const float* __restrict__ K, float* __restrict__ TOP)
{
    const int b  = blockIdx.x;           // 512 blocks = 8 n * 64 q-tiles
    const int n  = b >> 6;
    const int q0 = (b & 63) * TQ;
    const float* Qb = Q + ((size_t)n*TS + q0) * CD;
    const float* Kb = K + (size_t)n*TS*CD;
    const int tid = threadIdx.x;
    const int tj = tid & 31, tq = tid >> 5;   // tq in [0,8): rows tq*4..tq*4+3

    __shared__ float smem[TJ*SKS + TQ*CD];    // 34816B (sK) + 16384B (sQ) = 50 KB
    float* sKf = smem;                        // [TJ][SKS] row-major K tile chunk
    float* sQ  = smem + TJ*SKS;               // [TQ][CD]  row-major Q tile

    {   // stage Q tile (32x128 contiguous floats = 1024 float4)
        const float4* src = (const float4*)Qb;
        float4* dst = (float4*)sQ;
        #pragma unroll
        for (int i = 0; i < 4; i++) dst[tid + 256*i] = src[tid + 256*i];
    }

    // per-thread running top-3 for each of 4 owned rows
    float t0v[4], t1v[4], t2v[4];
    int   t0i[4], t1i[4], t2i[4];
    #pragma unroll
    for (int i = 0; i < 4; i++) {
        t0v[i] = t1v[i] = t2v[i] = -3e38f;
        t0i[i] = t1i[i] = t2i[i] = 0;
    }

    for (int j0 = 0; j0 < TS; j0 += TJ) {
        float acc[4][4];
        #pragma unroll
        for (int i = 0; i < 4; i++)
            #pragma unroll
            for (int u = 0; u < 4; u++) acc[i][u] = 0.f;

        #pragma unroll 1
        for (int cc = 0; cc < CD; cc += CCK) {
            __syncthreads();   // previous chunk's reads complete
            #pragma unroll
            for (int i = 0; i < 8; i++) {      // stage K chunk row-major
                int x = tid + 256*i;           // 0..2047 float4 slots
                int j = x >> 4, f4 = (x & 15) * 4;
                float4 v = *(const float4*)(Kb + (size_t)(j0 + j)*CD + cc + f4);
                *(float4*)&sKf[(size_t)j*SKS + f4] = v;
            }
            __syncthreads();
            #pragma unroll 4
            for (int c4 = 0; c4 < CCK/4; c4++) {
                const int c = 4*c4;
                float4 k0 = *(const float4*)&sKf[(size_t)(tj     )*SKS + c];
                float4 k1 = *(const float4*)&sKf[(size_t)(tj + 32)*SKS + c];
                float4 k2 = *(const float4*)&sKf[(size_t)(tj + 64)*SKS + c];
                float4 k3 = *(const float4*)&sKf[(size_t)(tj + 96)*SKS + c];
                #pragma unroll
                for (int i = 0; i < 4; i++) {
                    float4 q = *(const float4*)&sQ[(size_t)(tq*4+i)*CD + cc + c];
                    acc[i][0] += q.x*k0.x + q.y*k0.y + q.z*k0.z + q.w*k0.w;
                    acc[i][1] += q.x*k1.x + q.y*k1.y + q.z*k1.z + q.w*k1.w;
                    acc[i][2] += q.x*k2.x + q.y*k2.y + q.z*k2.z + q.w*k2.w;
                    acc[i][3] += q.x*k3.x + q.y*k3.y + q.z*k3.z + q.w*k3.w;
                }
            }
        }
        // register top-3 update (cols ascending: u=0..3 keeps earliest-index on ties)
        #pragma unroll
        for (int i = 0; i < 4; i++) {
            #pragma unroll
            for (int u = 0; u < 4; u++) {
                float v = acc[i][u];
                if (v > t2v[i]) {
                    int jg = j0 + tj + 32*u;
                    if (v > t0v[i]) {
                        t2v[i]=t1v[i]; t2i[i]=t1i[i];
                        t1v[i]=t0v[i]; t1i[i]=t0i[i];
                        t0v[i]=v;      t0i[i]=jg;
                    } else if (v > t1v[i]) {
                        t2v[i]=t1v[i]; t2i[i]=t1i[i];
                        t1v[i]=v;      t1i[i]=jg;
                    } else {
                        t2v[i]=v;      t2i[i]=jg;
                    }
                }
            }
        }
    }

    // ---- final merge: 32 candidates x3 per row -> top-3 ----
    __syncthreads();                       // all sK reads done; overlay merge buf
    float* mrg = smem;                     // [32 rows][MRS]; uses 6176 floats < sK
    #pragma unroll
    for (int i = 0; i < 4; i++) {
        float* m = &mrg[(size_t)(tq*4+i)*MRS + tj*6];
        m[0] = t0v[i]; m[1] = __int_as_float(t0i[i]);
        m[2] = t1v[i]; m[3] = __int_as_float(t1i[i]);
        m[4] = t2v[i]; m[5] = __int_as_float(t2i[i]);
    }
    __syncthreads();
    if (tid < TQ) {
        float b0v = -3e38f, b1v = -3e38f, b2v = -3e38f;
        int   b0i = 0x7fffffff, b1i = 0x7fffffff, b2i = 0x7fffffff;
        const float* m = &mrg[(size_t)tid*MRS];
        for (int t2 = 0; t2 < 32; t2++) {
            #pragma unroll
            for (int k = 0; k < 3; k++) {
                float v = m[t2*6 + 2*k];
                int  id = __float_as_int(m[t2*6 + 2*k + 1]);
                bool g2 = (v > b2v) || (v == b2v && id < b2i);
                if (g2) {
                    bool g0 = (v > b0v) || (v == b0v && id < b0i);
                    bool g1 = (v > b1v) || (v == b1v && id < b1i);
                    if (g0)      { b2v=b1v;b2i=b1i; b1v=b0v;b1i=b0i; b0v=v;b0i=id; }
                    else if (g1) { b2v=b1v;b2i=b1i; b1v=v;  b1i=id; }
                    else         { b2v=v;  b2i=id; }
                }
            }
        }
        const int row = n*TS + q0 + tid;
        float e1 = __expf((b1v - b0v)*SCALE);
        float e2 = __expf((b2v - b0v)*SCALE);
        float rz = 1.0f / (1.0f + e1 + e2);
        float* dst = TOP + (size_t)row*8;
        dst[0] = rz; dst[1] = e1*rz; dst[2] = e2*rz;
        int* di = (int*)dst;
        di[4] = b0i; di[5] = b1i; di[6] = b2i;
    }
}

// ---- Kernel 3: materialize dense fp32 attention (zeros + 3 probs per row) ----
__global__ __launch_bounds__(256) void attn_write(
    const float* __restrict__ TOP, float* __restrict__ A)
{
    const int r = blockIdx.x, t = threadIdx.x;
    const float* s = TOP + (size_t)r*8;        // uniform -> scalar loads
    const int* si = (const int*)s;
    float p0 = s[0], p1 = s[1], p2 = s[2];
    int i0 = si[4], i1 = si[5], i2 = si[6];
    const int col0 = t*8;
    float vals[8];
    #pragma unroll
    for (int u = 0; u < 8; u++) {
        int col = col0 + u;
        float v = 0.f;
        if (col == i0) v = p0;
        if (col == i1) v = p1;
        if (col == i2) v = p2;
        vals[u] = v;
    }
    float4* dst = (float4*)(A + (size_t)r*TS + col0);
    dst[0] = make_float4(vals[0], vals[1], vals[2], vals[3]);
    dst[1] = make_float4(vals[4], vals[5], vals[6], vals[7]);
}

// ---- Kernel 4: out = (sum_k p_k * E[i_k]) @ Wo^T + bo, 8 rows per block ----
__global__ __launch_bounds__(128) void out_proj(
    const float* __restrict__ E, const float* __restrict__ Wo,
    const float* __restrict__ bo, const float* __restrict__ TOP,
    float* __restrict__ OUT)
{
    const int r0 = blockIdx.x * RPB, t = threadIdx.x;
    const int n = r0 >> 11;    // all 8 rows share n (T divisible by RPB)
    __shared__ float o[RPB][CD];
    #pragma unroll
    for (int i = 0; i < RPB; i++) {
        const float* s = TOP + (size_t)(r0+i)*8;
        const int* si = (const int*)s;
        const float* e0 = E + ((size_t)n*TS + si[4])*CD;
        const float* e1 = E + ((size_t)n*TS + si[5])*CD;
        const float* e2 = E + ((size_t)n*TS + si[6])*CD;
        o[i][t] = s[0]*e0[t] + s[1]*e1[t] + s[2]*e2[t];
    }
    __syncthreads();
    const float* wr = Wo + (size_t)t*CD;
    float acc[RPB];
    float bias = bo[t];
    #pragma unroll
    for (int i = 0; i < RPB; i++) acc[i] = bias;
    #pragma unroll
    for (int c = 0; c < CD; c += 4) {
        float4 a = *(const float4*)(wr + c);
        #pragma unroll
        for (int i = 0; i < RPB; i++)
            acc[i] += a.x*o[i][c+0] + a.y*o[i][c+1] + a.z*o[i][c+2] + a.w*o[i][c+3];
    }
    #pragma unroll
    for (int i = 0; i < RPB; i++)
        OUT[(size_t)(r0+i)*CD + t] = acc[i];
}

extern "C" void kernel_launch(void* const* d_in, const int* in_sizes, int n_in,
                              void* d_out, int out_size, void* d_ws, size_t ws_size,
                              hipStream_t stream)
{
    const float* E  = (const float*)d_in[0];
    // d_in[1] = ac, unused by the forward pass
    const float* Wq = (const float*)d_in[2];
    const float* Wk = (const float*)d_in[3];
    const float* Wo = (const float*)d_in[4];
    const float* bo = (const float*)d_in[5];

    float* Q   = (float*)d_ws;                       // 16384x128 fp32 (8 MB)
    float* K   = Q + (size_t)NROWS*CD;               // 8 MB
    float* TOP = K + (size_t)NROWS*CD;               // 16384x8 fp32 (512 KB)

    float* OUT = (float*)d_out;                      // [N,T,C] fp32
    float* A   = OUT + (size_t)NROWS*CD;             // [N,1,T,T] fp32

    proj_qk    <<<NROWS/RPB, 128, 0, stream>>>(E, Wq, Wk, Q, K);
    scores_top3<<<512,       256, 0, stream>>>(Q, K, TOP);
    attn_write <<<NROWS,     256, 0, stream>>>(TOP, A);
    out_proj   <<<NROWS/RPB, 128, 0, stream>>>(E, Wo, bo, TOP, OUT);
}

// Round 5
// 387.559 us; speedup vs baseline: 1.2206x; 1.1011x over previous
//
#include <hip/hip_runtime.h>
#include <stdint.h>

#define TS 2048
#define CD 128
#define NB 8
#define NROWS (NB*TS)          // 16384
#define RPB 8                  // rows per block in projection kernels
#define SCALE 0.08838834764831845f  // 1/sqrt(128)

// ---- scores kernel geometry ----
#define TQ 64                  // q-rows per block
#define TJ 256                 // j-tile width
#define JSPLIT 4
#define JRANGE (TS/JSPLIT)     // 512 -> 2 tiles per block
#define CK 16                  // c-chunk staged per sync
#define SKSTRIDE 260           // sK row stride in float4 (256 + 4 pad)
#define SQ_FLOATS (TQ*CD)                  // 8192
#define SK_FLOATS (4*SKSTRIDE*4)           // 4160
#define SMEM_FLOATS (SQ_FLOATS + SK_FLOATS) // 12352 floats = 49408 B
#define CSTRIDE 193            // candidate merge row stride (32*6+1)

// ---- Kernel 1: Q = E@Wq^T, K = E@Wk^T (fp32), 8 rows per block ----
__global__ __launch_bounds__(128) void proj_qk(
    const float* __restrict__ E, const float* __restrict__ Wq,
    const float* __restrict__ Wk, float* __restrict__ Q, float* __restrict__ K)
{
    const int r0 = blockIdx.x * RPB, t = threadIdx.x;
    __shared__ float e[RPB][CD];
    {
        const float4* src = (const float4*)(E + (size_t)r0*CD);
        float4* dst = (float4*)&e[0][0];
        dst[t] = src[t];
        dst[t + 128] = src[t + 128];
    }
    __syncthreads();
    const float* wq = Wq + (size_t)t*CD;
    const float* wk = Wk + (size_t)t*CD;
    float aq[RPB], ak[RPB];
    #pragma unroll
    for (int i = 0; i < RPB; i++) { aq[i] = 0.f; ak[i] = 0.f; }
    #pragma unroll
    for (int c = 0; c < CD; c += 4) {
        float4 a = *(const float4*)(wq + c);
        float4 b = *(const float4*)(wk + c);
        #pragma unroll
        for (int i = 0; i < RPB; i++) {
            float e0 = e[i][c+0], e1 = e[i][c+1], e2 = e[i][c+2], e3 = e[i][c+3];
            aq[i] += a.x*e0 + a.y*e1 + a.z*e2 + a.w*e3;
            ak[i] += b.x*e0 + b.y*e1 + b.z*e2 + b.w*e3;
        }
    }
    #pragma unroll
    for (int i = 0; i < RPB; i++) {
        Q[(size_t)(r0+i)*CD + t] = aq[i];
        K[(size_t)(r0+i)*CD + t] = ak[i];
    }
}

// ---- Kernel 2: scores tile GEMM + per-thread top-3, per-(row,split) result ----
__global__ __launch_bounds__(256, 3) void scores_top3(
    const float* __restrict__ Q, const float* __restrict__ K, float* __restrict__ SPL)
{
    const int b  = blockIdx.x;           // 1024 = 8 n * 32 qtiles * 4 splits
    const int n  = b >> 7;
    const int qt = (b >> 2) & 31;
    const int sp = b & 3;
    const int q0 = qt * TQ;
    const int jb = sp * JRANGE;
    const float* Kb = K + (size_t)n*TS*CD;
    const int tid = threadIdx.x;
    const int tj = tid & 31, tq = tid >> 5;   // tq in [0,8): rows tq*8..tq*8+7

    __shared__ float smem[SMEM_FLOATS];
    float*  sQ = smem;                        // [TQ][CD] row-major
    float4* sK = (float4*)(smem + SQ_FLOATS); // [4 c4-groups][SKSTRIDE]

    {   // stage Q tile: 64x128 floats = 2048 float4, 8 per thread
        const float4* src = (const float4*)(Q + ((size_t)n*TS + q0)*CD);
        float4* dst = (float4*)sQ;
        #pragma unroll
        for (int i = 0; i < 8; i++) dst[tid + 256*i] = src[tid + 256*i];
    }

    // per-thread running top-3 for each of 8 owned rows
    float t0v[8], t1v[8], t2v[8];
    int   t0i[8], t1i[8], t2i[8];
    #pragma unroll
    for (int i = 0; i < 8; i++) {
        t0v[i] = t1v[i] = t2v[i] = -3e38f;
        t0i[i] = t1i[i] = t2i[i] = 0;
    }

    #pragma unroll 1
    for (int jt = 0; jt < JRANGE/TJ; jt++) {
        const int j0 = jb + jt*TJ;
        float acc[8][8];
        #pragma unroll
        for (int i = 0; i < 8; i++)
            #pragma unroll
            for (int u = 0; u < 8; u++) acc[i][u] = 0.f;

        #pragma unroll 1
        for (int cc = 0; cc < CD; cc += CK) {
            __syncthreads();   // previous chunk's reads (and Q staging) done
            #pragma unroll
            for (int s = 0; s < 4; s++) {   // stage K: 256 rows x 16 c, c4-grouped
                int j  = (tid >> 2) + 64*s;
                int c4 = tid & 3;
                float4 v = *(const float4*)(Kb + (size_t)(j0 + j)*CD + cc + c4*4);
                sK[c4*SKSTRIDE + j] = v;
            }
            __syncthreads();
            #pragma unroll
            for (int c4 = 0; c4 < 4; c4++) {
                float4 kf[8];
                #pragma unroll
                for (int u = 0; u < 8; u++) kf[u] = sK[c4*SKSTRIDE + tj + 32*u];
                #pragma unroll
                for (int i = 0; i < 8; i++) {
                    float4 qf = *(const float4*)&sQ[(size_t)(tq*8+i)*CD + cc + c4*4];
                    #pragma unroll
                    for (int u = 0; u < 8; u++) {
                        acc[i][u] = __builtin_fmaf(qf.x, kf[u].x, acc[i][u]);
                        acc[i][u] = __builtin_fmaf(qf.y, kf[u].y, acc[i][u]);
                        acc[i][u] = __builtin_fmaf(qf.z, kf[u].z, acc[i][u]);
                        acc[i][u] = __builtin_fmaf(qf.w, kf[u].w, acc[i][u]);
                    }
                }
            }
        }
        // register top-3 update (u ascending keeps earliest index on ties)
        #pragma unroll
        for (int i = 0; i < 8; i++) {
            #pragma unroll
            for (int u = 0; u < 8; u++) {
                float v = acc[i][u];
                if (v > t2v[i]) {
                    int jg = j0 + tj + 32*u;
                    if (v > t0v[i]) {
                        t2v[i]=t1v[i]; t2i[i]=t1i[i];
                        t1v[i]=t0v[i]; t1i[i]=t0i[i];
                        t0v[i]=v;      t0i[i]=jg;
                    } else if (v > t1v[i]) {
                        t2v[i]=t1v[i]; t2i[i]=t1i[i];
                        t1v[i]=v;      t1i[i]=jg;
                    } else {
                        t2v[i]=v;      t2i[i]=jg;
                    }
                }
            }
        }
    }

    // ---- block merge: 32 threads x3 candidates per row -> per-(row,split) top-3 ----
    __syncthreads();                       // all sK/sQ reads done; overlay buffer
    float* cand = smem;                    // [64 rows][CSTRIDE]; 64*193 = 12352 floats
    #pragma unroll
    for (int i = 0; i < 8; i++) {
        float* m = &cand[(size_t)(tq*8+i)*CSTRIDE + tj*6];
        m[0] = t0v[i]; m[1] = __int_as_float(t0i[i]);
        m[2] = t1v[i]; m[3] = __int_as_float(t1i[i]);
        m[4] = t2v[i]; m[5] = __int_as_float(t2i[i]);
    }
    __syncthreads();
    if (tid < TQ) {
        float b0v = -3e38f, b1v = -3e38f, b2v = -3e38f;
        int   b0i = 0x7fffffff, b1i = 0x7fffffff, b2i = 0x7fffffff;
        const float* m = &cand[(size_t)tid*CSTRIDE];
        for (int t2 = 0; t2 < 32; t2++) {
            #pragma unroll
            for (int k = 0; k < 3; k++) {
                float v = m[t2*6 + 2*k];
                int  id = __float_as_int(m[t2*6 + 2*k + 1]);
                bool g2 = (v > b2v) || (v == b2v && id < b2i);
                if (g2) {
                    bool g0 = (v > b0v) || (v == b0v && id < b0i);
                    bool g1 = (v > b1v) || (v == b1v && id < b1i);
                    if (g0)      { b2v=b1v;b2i=b1i; b1v=b0v;b1i=b0i; b0v=v;b0i=id; }
                    else if (g1) { b2v=b1v;b2i=b1i; b1v=v;  b1i=id; }
                    else         { b2v=v;  b2i=id; }
                }
            }
        }
        const int row = n*TS + q0 + tid;
        float* dst = SPL + ((size_t)row*JSPLIT + sp)*8;
        dst[0] = b0v; dst[1] = __int_as_float(b0i);
        dst[2] = b1v; dst[3] = __int_as_float(b1i);
        dst[4] = b2v; dst[5] = __int_as_float(b2i);
    }
}

// ---- Kernel 3: merge 4 splits per row -> global top-3 + 3-term softmax ----
__global__ __launch_bounds__(256) void merge_splits(
    const float* __restrict__ SPL, float* __restrict__ TOP)
{
    const int row = blockIdx.x*256 + threadIdx.x;   // 64 blocks -> 16384 rows
    const float* s = SPL + (size_t)row*JSPLIT*8;
    float b0v = -3e38f, b1v = -3e38f, b2v = -3e38f;
    int   b0i = 0x7fffffff, b1i = 0x7fffffff, b2i = 0x7fffffff;
    #pragma unroll
    for (int sp = 0; sp < JSPLIT; sp++) {
        #pragma unroll
        for (int k = 0; k < 3; k++) {
            float v = s[sp*8 + 2*k];
            int  id = __float_as_int(s[sp*8 + 2*k + 1]);
            bool g2 = (v > b2v) || (v == b2v && id < b2i);
            if (g2) {
                bool g0 = (v > b0v) || (v == b0v && id < b0i);
                bool g1 = (v > b1v) || (v == b1v && id < b1i);
                if (g0)      { b2v=b1v;b2i=b1i; b1v=b0v;b1i=b0i; b0v=v;b0i=id; }
                else if (g1) { b2v=b1v;b2i=b1i; b1v=v;  b1i=id; }
                else         { b2v=v;  b2i=id; }
            }
        }
    }
    float e1 = __expf((b1v - b0v)*SCALE);
    float e2 = __expf((b2v - b0v)*SCALE);
    float rz = 1.0f / (1.0f + e1 + e2);
    float* dst = TOP + (size_t)row*8;
    dst[0] = rz; dst[1] = e1*rz; dst[2] = e2*rz;
    int* di = (int*)dst;
    di[4] = b0i; di[5] = b1i; di[6] = b2i;
}

// ---- Kernel 4: materialize dense fp32 attention (zeros + 3 probs per row) ----
__global__ __launch_bounds__(256) void attn_write(
    const float* __restrict__ TOP, float* __restrict__ A)
{
    const int r = blockIdx.x, t = threadIdx.x;
    const float* s = TOP + (size_t)r*8;
    const int* si = (const int*)s;
    float p0 = s[0], p1 = s[1], p2 = s[2];
    int i0 = si[4], i1 = si[5], i2 = si[6];
    const int col0 = t*8;
    float vals[8];
    #pragma unroll
    for (int u = 0; u < 8; u++) {
        int col = col0 + u;
        float v = 0.f;
        if (col == i0) v = p0;
        if (col == i1) v = p1;
        if (col == i2) v = p2;
        vals[u] = v;
    }
    float4* dst = (float4*)(A + (size_t)r*TS + col0);
    dst[0] = make_float4(vals[0], vals[1], vals[2], vals[3]);
    dst[1] = make_float4(vals[4], vals[5], vals[6], vals[7]);
}

// ---- Kernel 5: out = (sum_k p_k * E[i_k]) @ Wo^T + bo, 8 rows per block ----
__global__ __launch_bounds__(128) void out_proj(
    const float* __restrict__ E, const float* __restrict__ Wo,
    const float* __restrict__ bo, const float* __restrict__ TOP,
    float* __restrict__ OUT)
{
    const int r0 = blockIdx.x * RPB, t = threadIdx.x;
    const int n = r0 >> 11;
    __shared__ float o[RPB][CD];
    #pragma unroll
    for (int i = 0; i < RPB; i++) {
        const float* s = TOP + (size_t)(r0+i)*8;
        const int* si = (const int*)s;
        const float* e0 = E + ((size_t)n*TS + si[4])*CD;
        const float* e1 = E + ((size_t)n*TS + si[5])*CD;
        const float* e2 = E + ((size_t)n*TS + si[6])*CD;
        o[i][t] = s[0]*e0[t] + s[1]*e1[t] + s[2]*e2[t];
    }
    __syncthreads();
    const float* wr = Wo + (size_t)t*CD;
    float acc[RPB];
    float bias = bo[t];
    #pragma unroll
    for (int i = 0; i < RPB; i++) acc[i] = bias;
    #pragma unroll
    for (int c = 0; c < CD; c += 4) {
        float4 a = *(const float4*)(wr + c);
        #pragma unroll
        for (int i = 0; i < RPB; i++)
            acc[i] += a.x*o[i][c+0] + a.y*o[i][c+1] + a.z*o[i][c+2] + a.w*o[i][c+3];
    }
    #pragma unroll
    for (int i = 0; i < RPB; i++)
        OUT[(size_t)(r0+i)*CD + t] = acc[i];
}

extern "C" void kernel_launch(void* const* d_in, const int* in_sizes, int n_in,
                              void* d_out, int out_size, void* d_ws, size_t ws_size,
                              hipStream_t stream)
{
    const float* E  = (const float*)d_in[0];
    // d_in[1] = ac, unused by the forward pass
    const float* Wq = (const float*)d_in[2];
    const float* Wk = (const float*)d_in[3];
    const float* Wo = (const float*)d_in[4];
    const float* bo = (const float*)d_in[5];

    float* Q   = (float*)d_ws;                       // 16384x128 fp32 (8 MB)
    float* K   = Q + (size_t)NROWS*CD;               // 8 MB
    float* TOP = K + (size_t)NROWS*CD;               // 16384x8 fp32 (512 KB)

    float* OUT = (float*)d_out;                      // [N,T,C] fp32
    float* A   = OUT + (size_t)NROWS*CD;             // [N,1,T,T] fp32
    float* SPL = A;   // scratch: 16384x4x8 fp32 = 2 MB, parked in A,
                      // fully overwritten by attn_write afterwards

    proj_qk     <<<NROWS/RPB, 128, 0, stream>>>(E, Wq, Wk, Q, K);
    scores_top3 <<<NB*(TS/TQ)*JSPLIT, 256, 0, stream>>>(Q, K, SPL);
    merge_splits<<<NROWS/256, 256, 0, stream>>>(SPL, TOP);
    attn_write  <<<NROWS,     256, 0, stream>>>(TOP, A);
    out_proj    <<<NROWS/RPB, 128, 0, stream>>>(E, Wo, bo, TOP, OUT);
}